// Round 1
// baseline (1176.843 us; speedup 1.0000x reference)
//
#include <hip/hip_runtime.h>
#include <hip/hip_bf16.h>
#include <stdint.h>

// Problem constants (z: [16,256,32,32] fp32, emb: [8192,256] fp32)
#define NB   16
#define CD   256
#define HW   1024          // 32*32
#define NQ   16384         // NB*HW
#define KCN  8192          // codebook entries

// ---------------- workspace layout ----------------
// zT   : float [NQ][CD]    @ 0          (16 MB)  -- z transposed to [query][c]
// cand : u64   [NQ][8]     @ 16777216   (1 MB)   -- top-2 packed (distbits,idx) x 4 splits
// idxF : int   [NQ]        @ 17825792   (64 KB)
// eSq  : float [KCN]       @ 17891328   (32 KB)
// total ~17.1 MB
#define ZT_OFF   0
#define CAND_OFF 16777216
#define IDX_OFF  17825792
#define ESQ_OFF  17891328

// ---------------- kernel 1: transpose z [b][c][hw] -> zT [b*HW+hw][c] ----------------
__global__ __launch_bounds__(256) void k_transpose(const float* __restrict__ z,
                                                   float* __restrict__ zT) {
  __shared__ float tile[64][65];
  const int bx  = blockIdx.x;          // 16 b * 16 hwT * 4 cT = 1024 blocks
  const int b   = bx >> 6;
  const int hwT = (bx >> 2) & 15;
  const int cT  = bx & 3;
  const int tx  = threadIdx.x & 63;
  const int ty  = threadIdx.x >> 6;    // 0..3

  const float* src = z + (size_t)(b * CD + cT * 64) * HW + hwT * 64;
#pragma unroll
  for (int i = 0; i < 16; ++i) {
    const int c_l = ty + 4 * i;                 // 0..63
    tile[c_l][tx] = src[(size_t)c_l * HW + tx]; // coalesced along hw
  }
  __syncthreads();
  float* dst = zT + (size_t)(b * HW + hwT * 64) * CD + cT * 64;
#pragma unroll
  for (int i = 0; i < 16; ++i) {
    const int hw_l = ty + 4 * i;
    dst[(size_t)hw_l * CD + tx] = tile[tx][hw_l]; // coalesced along c
  }
}

// ---------------- kernel 2: eSq[k] = sum_c emb[k][c]^2 ----------------
__global__ __launch_bounds__(256) void k_esq(const float* __restrict__ emb,
                                             float* __restrict__ eSq) {
  const int wave = (int)((blockIdx.x * 256 + threadIdx.x) >> 6); // 0..127 (grid 32)
  const int lane = threadIdx.x & 63;
  for (int it = 0; it < 64; ++it) {
    const int row = wave + it * 128;
    const float4 v = *(const float4*)(emb + (size_t)row * CD + lane * 4);
    float s = v.x * v.x + v.y * v.y + v.z * v.z + v.w * v.w;
#pragma unroll
    for (int off = 32; off; off >>= 1) s += __shfl_xor(s, off, 64);
    if (lane == 0) eSq[row] = s;
  }
}

// ---------------- kernel 3: fused GEMM + top-2 argmin (fp32 main pass) ----------------
// Tile: TM=128 queries x TN=128 codes, TK=32; block 256 = 16(tx) x 16(ty);
// per-thread 8x8 register tile: q = ty + 16*r, n = tx + 16*s (interleaved for LDS banks).
// N split 4 ways (grid = 128 q-tiles * 4 splits); each split writes its own top-2 slots.
#define TM 128
#define TN 128
#define TK 32
#define NSPLIT 4
#define SPLITK (KCN / NSPLIT)   // 2048
#define NTILES (SPLITK / TN)    // 16

__global__ __launch_bounds__(256, 2) void k_argmin(const float* __restrict__ zT,
                                                   const float* __restrict__ emb,
                                                   const float* __restrict__ eSq,
                                                   unsigned long long* __restrict__ cand) {
  __shared__ float zs[TM][TK + 4];  // stride 36 floats: q-read banks 4*ty (conflict-free)
  __shared__ float es[TN][TK + 4];  // e-read banks 4*tx mod 32 (2-way, free)
  const int t  = threadIdx.x;
  const int tx = t & 15;
  const int ty = t >> 4;
  const int qt    = blockIdx.x >> 2;
  const int split = blockIdx.x & 3;
  const int q0    = qt * TM;
  const int nbase = split * SPLITK;

  unsigned long long b1[8], b2[8];
#pragma unroll
  for (int r = 0; r < 8; ++r) { b1[r] = ~0ull; b2[r] = ~0ull; }

  const int srow = t >> 3;         // 0..31
  const int scol = (t & 7) * 4;    // 0..28

  for (int nt = 0; nt < NTILES; ++nt) {
    const int n0 = nbase + nt * TN;
    float acc[8][8];
#pragma unroll
    for (int r = 0; r < 8; ++r)
#pragma unroll
      for (int s = 0; s < 8; ++s) acc[r][s] = 0.f;

    for (int kc = 0; kc < CD / TK; ++kc) {  // 8 chunks of K
      __syncthreads();
#pragma unroll
      for (int i = 0; i < 4; ++i) {
        const int row = srow + i * 32;      // 0..127
        *(float4*)&zs[row][scol] =
            *(const float4*)(zT + (size_t)(q0 + row) * CD + kc * TK + scol);
        *(float4*)&es[row][scol] =
            *(const float4*)(emb + (size_t)(n0 + row) * CD + kc * TK + scol);
      }
      __syncthreads();
#pragma unroll
      for (int c = 0; c < TK; c += 4) {
        float4 zr[8];
#pragma unroll
        for (int r = 0; r < 8; ++r) zr[r] = *(const float4*)&zs[ty + 16 * r][c];
#pragma unroll
        for (int s = 0; s < 8; ++s) {
          const float4 e = *(const float4*)&es[tx + 16 * s][c];
#pragma unroll
          for (int r = 0; r < 8; ++r) {
            acc[r][s] = fmaf(zr[r].x, e.x, acc[r][s]);
            acc[r][s] = fmaf(zr[r].y, e.y, acc[r][s]);
            acc[r][s] = fmaf(zr[r].z, e.z, acc[r][s]);
            acc[r][s] = fmaf(zr[r].w, e.w, acc[r][s]);
          }
        }
      }
    }
    // epilogue: d = ||e||^2 - 2 z.e  (||z||^2 constant per query, dropped)
#pragma unroll
    for (int s = 0; s < 8; ++s) {
      const int n = n0 + tx + 16 * s;
      const float esq = __ldg(eSq + n);
#pragma unroll
      for (int r = 0; r < 8; ++r) {
        const float d = fmaf(-2.f, acc[r][s], esq);
        unsigned u = __float_as_uint(d);
        u = (u & 0x80000000u) ? ~u : (u | 0x80000000u);  // order-preserving map
        const unsigned long long p = ((unsigned long long)u << 32) | (unsigned)n;
        const unsigned long long loser = p > b1[r] ? p : b1[r];
        b1[r] = p < b1[r] ? p : b1[r];
        b2[r] = loser < b2[r] ? loser : b2[r];
      }
    }
  }
  // cross-lane top-2 merge over the 16 tx lanes (xor butterfly stays in-group)
#pragma unroll
  for (int r = 0; r < 8; ++r) {
    unsigned long long x1 = b1[r], x2 = b2[r];
#pragma unroll
    for (int off = 1; off < 16; off <<= 1) {
      const unsigned long long o1 = __shfl_xor(x1, off, 64);
      const unsigned long long o2 = __shfl_xor(x2, off, 64);
      const unsigned long long lo = x1 < o1 ? x1 : o1;
      const unsigned long long hi = x1 < o1 ? o1 : x1;
      const unsigned long long m2 = x2 < o2 ? x2 : o2;
      x1 = lo;
      x2 = hi < m2 ? hi : m2;
    }
    if (tx == 0) {
      const int q = q0 + ty + 16 * r;
      cand[(size_t)q * 8 + split * 2 + 0] = x1;
      cand[(size_t)q * 8 + split * 2 + 1] = x2;
    }
  }
}

// ---------------- kernel 4: fp64 exact re-score of 8 candidates/query ----------------
__global__ __launch_bounds__(256) void k_rescore(const float* __restrict__ zT,
                                                 const float* __restrict__ emb,
                                                 const unsigned long long* __restrict__ cand,
                                                 int* __restrict__ idxF) {
  const int lane = threadIdx.x & 63;
  const int wv   = threadIdx.x >> 6;      // 0..3
  const int qbase = blockIdx.x * 64;      // grid 256
  for (int it = 0; it < 16; ++it) {
    const int q = qbase + wv * 16 + it;
    const float4 zv = *(const float4*)(zT + (size_t)q * CD + lane * 4);
    double bd = 1e300;
    int bi = 0x7fffffff;
#pragma unroll
    for (int j = 0; j < 8; ++j) {
      const int idx = (int)(cand[(size_t)q * 8 + j] & 0xffffffffull);
      const float4 ev = *(const float4*)(emb + (size_t)idx * CD + lane * 4);
      const double dx = (double)zv.x - (double)ev.x;
      const double dy = (double)zv.y - (double)ev.y;
      const double dz = (double)zv.z - (double)ev.z;
      const double dw = (double)zv.w - (double)ev.w;
      double s = dx * dx + dy * dy + dz * dz + dw * dw;
#pragma unroll
      for (int off = 32; off; off >>= 1) s += __shfl_xor(s, off, 64);
      if (s < bd || (s == bd && idx < bi)) { bd = s; bi = idx; }
    }
    if (lane == 0) idxF[q] = bi;
  }
}

// ---------------- kernel 5: gather + layout write out[b][c][hw] = emb[idx[n]][c] ----------------
__global__ __launch_bounds__(256) void k_gather(const float* __restrict__ emb,
                                                const int* __restrict__ idxF,
                                                float* __restrict__ out) {
  const int b   = blockIdx.x >> 2;           // grid 64
  const int hw0 = (blockIdx.x & 3) * 256;
  const int t   = threadIdx.x;
  const int n   = b * HW + hw0 + t;
  const int k   = idxF[n];
  const float* er = emb + (size_t)k * CD;
  float* ob = out + (size_t)b * CD * HW + hw0 + t;
#pragma unroll 2
  for (int c4 = 0; c4 < CD; c4 += 4) {
    const float4 e = *(const float4*)(er + c4);
    ob[(size_t)(c4 + 0) * HW] = e.x;  // coalesced across lanes (hw contiguous)
    ob[(size_t)(c4 + 1) * HW] = e.y;
    ob[(size_t)(c4 + 2) * HW] = e.z;
    ob[(size_t)(c4 + 3) * HW] = e.w;
  }
}

extern "C" void kernel_launch(void* const* d_in, const int* in_sizes, int n_in,
                              void* d_out, int out_size, void* d_ws, size_t ws_size,
                              hipStream_t stream) {
  const float* z   = (const float*)d_in[0];   // [16,256,32,32]
  const float* emb = (const float*)d_in[1];   // [8192,256]
  float* out = (float*)d_out;

  char* ws = (char*)d_ws;                     // needs ~17.1 MB
  float* zT                 = (float*)(ws + ZT_OFF);
  unsigned long long* cand  = (unsigned long long*)(ws + CAND_OFF);
  int* idxF                 = (int*)(ws + IDX_OFF);
  float* eSq                = (float*)(ws + ESQ_OFF);

  k_transpose<<<1024, 256, 0, stream>>>(z, zT);
  k_esq<<<32, 256, 0, stream>>>(emb, eSq);
  k_argmin<<<512, 256, 0, stream>>>(zT, emb, eSq, cand);
  k_rescore<<<256, 256, 0, stream>>>(zT, emb, cand, idxF);
  k_gather<<<64, 256, 0, stream>>>(emb, idxF, out);
}

// Round 3
// 296.232 us; speedup vs baseline: 3.9727x; 3.9727x over previous
//
#include <hip/hip_runtime.h>
#include <stdint.h>

#define NB   16
#define CD   256
#define HW   1024
#define NQ   16384
#define KCN  8192

typedef unsigned long long u64;
typedef unsigned short     u16;
using f32x4  = __attribute__((ext_vector_type(4))) float;
using bf16x8 = __attribute__((ext_vector_type(8))) __bf16;

// ---------------- workspace layout (~16.9 MB) ----------------
#define ZTB_OFF  0            // u16  [NQ][CD]   8 MB   (z transposed, bf16)
#define EMBB_OFF 8388608      // u16  [KCN][CD]  4 MB   (emb, bf16)
#define EH_OFF   12582912     // f32  [KCN]      32 KB  (||e||^2/2 + 1024)
#define CAND_OFF 12615680     // u64  [NQ][32]   4 MB   (8 splits x 2 wave-halves x top-2)
#define IDX_OFF  16809984     // int  [NQ]       64 KB

// canonical addrspacecast pattern (NOT via uintptr_t — that is inttoptr, wrong)
static __device__ __forceinline__ void gl_lds16(const void* g, void* l) {
  __builtin_amdgcn_global_load_lds(
      (const __attribute__((address_space(1))) void*)g,
      (__attribute__((address_space(3))) void*)l, 16, 0, 0);
}

static __device__ __forceinline__ unsigned bf16r(float x) {  // RNE fp32->bf16 bits
  unsigned u = __float_as_uint(x);
  return (u + 0x7fffu + ((u >> 16) & 1u)) >> 16;
}

static __device__ __forceinline__ u64 umin64(u64 a, u64 b) { return a < b ? a : b; }
static __device__ __forceinline__ u64 umax64(u64 a, u64 b) { return a < b ? b : a; }

// ---------------- kernel 1: z [b][c][hw] -> zTb bf16 [b*HW+hw][c] ----------------
__global__ __launch_bounds__(256) void k_prep_z(const float* __restrict__ z,
                                                u16* __restrict__ zTb) {
  __shared__ float tile[64][65];
  const int bx  = blockIdx.x;          // 16 b * 16 hwT * 4 cT = 1024
  const int b   = bx >> 6;
  const int hwT = (bx >> 2) & 15;
  const int cT  = bx & 3;
  const int tx  = threadIdx.x & 63;
  const int ty  = threadIdx.x >> 6;

  const float* src = z + (size_t)(b * CD + cT * 64) * HW + hwT * 64;
#pragma unroll
  for (int i = 0; i < 16; ++i) {
    const int c_l = ty + 4 * i;
    tile[c_l][tx] = src[(size_t)c_l * HW + tx];
  }
  __syncthreads();
  u16* dst = zTb + (size_t)(b * HW + hwT * 64) * CD + cT * 64;
#pragma unroll
  for (int i = 0; i < 16; ++i) {
    const int hw_l = ty + 4 * i;
    dst[(size_t)hw_l * CD + tx] = (u16)bf16r(tile[tx][hw_l]);
  }
}

// ---------------- kernel 2: embB bf16 + eH = ||e||^2/2 + 1024 ----------------
__global__ __launch_bounds__(256) void k_prep_e(const float* __restrict__ emb,
                                                u16* __restrict__ embB,
                                                float* __restrict__ eH) {
  const int wave = (int)((blockIdx.x * 256 + threadIdx.x) >> 6);  // 0..127
  const int lane = threadIdx.x & 63;
  for (int it = 0; it < 64; ++it) {
    const int row = wave + it * 128;
    const float4 v = *(const float4*)(emb + (size_t)row * CD + lane * 4);
    uint2 pk;
    pk.x = bf16r(v.x) | (bf16r(v.y) << 16);
    pk.y = bf16r(v.z) | (bf16r(v.w) << 16);
    *(uint2*)(embB + (size_t)row * CD + lane * 4) = pk;
    float s = v.x * v.x + v.y * v.y + v.z * v.z + v.w * v.w;
#pragma unroll
    for (int off = 32; off; off >>= 1) s += __shfl_xor(s, off, 64);
    if (lane == 0) eH[row] = 0.5f * s + 1024.0f;
  }
}

// ---------------- kernel 3: MFMA GEMM + fused top-2 argmin ----------------
// grid = 128 q-tiles * 8 splits; block 256 = 4 waves, wave w covers
// queries wq0=(w&1)*64 .. +64, codes wn0=(w>>1)*64 .. +64 of the 128x128 tile.
// K=256 in 4 chunks of BK=64; LDS tiles [128 rows][64 bf16] FLAT (m97 layout).
// Wave-halves (w>>1) hold disjoint code ranges -> write DISJOINT cand slots.
#define NT  8
#define BKC 4

__global__ __launch_bounds__(256, 2) void k_argmin(const u16* __restrict__ zTb,
                                                   const u16* __restrict__ embB,
                                                   const float* __restrict__ eH,
                                                   u64* __restrict__ cand) {
  __shared__ __align__(16) u16 As[128 * 64];
  __shared__ __align__(16) u16 Bs[128 * 64];
  const int tid  = threadIdx.x;
  const int w    = tid >> 6;
  const int lane = tid & 63;
  const int l15  = lane & 15, quad = lane >> 4;
  const int q0    = (blockIdx.x >> 3) * 128;
  const int split = blockIdx.x & 7;
  const int wq0 = (w & 1) * 64, wn0 = (w >> 1) * 64, wh = w >> 1;

  // staging: wave w stages rows [w*32, w*32+32) of both tiles, flat order
  const int srow  = w * 32 + (lane >> 3);     // + i*8
  const int scol8 = (lane & 7) * 8;           // element offset within BK=64
  const int ldsL  = w * 4096 + lane * 16;     // byte offset, + i*1024

  u64 b1[16], b2[16];
#pragma unroll
  for (int s = 0; s < 16; ++s) { b1[s] = ~0ull; b2[s] = ~0ull; }

  for (int nt = 0; nt < NT; ++nt) {
    const int n0 = split * 1024 + nt * 128;
    float eh[4];
#pragma unroll
    for (int j = 0; j < 4; ++j) eh[j] = eH[n0 + wn0 + 16 * j + l15];

    f32x4 acc[4][4];
#pragma unroll
    for (int i = 0; i < 4; ++i)
#pragma unroll
      for (int j = 0; j < 4; ++j) acc[i][j] = f32x4{0.f, 0.f, 0.f, 0.f};

    for (int kc = 0; kc < BKC; ++kc) {
#pragma unroll
      for (int i = 0; i < 4; ++i) {
        const int row = srow + i * 8;
        gl_lds16(zTb  + (size_t)(q0 + row) * CD + kc * 64 + scol8,
                 (char*)As + ldsL + i * 1024);
        gl_lds16(embB + (size_t)(n0 + row) * CD + kc * 64 + scol8,
                 (char*)Bs + ldsL + i * 1024);
      }
      __syncthreads();  // drains vmcnt (async LDS writes visible)
#pragma unroll
      for (int ks = 0; ks < 2; ++ks) {
        const int co = ks * 64 + quad * 16;   // byte offset: k = ks*32 + quad*8
        bf16x8 af[4], bfr[4];
#pragma unroll
        for (int i = 0; i < 4; ++i)
          af[i] = *(const bf16x8*)((const char*)As + (wq0 + i * 16 + l15) * 128 + co);
#pragma unroll
        for (int j = 0; j < 4; ++j)
          bfr[j] = *(const bf16x8*)((const char*)Bs + (wn0 + j * 16 + l15) * 128 + co);
#pragma unroll
        for (int i = 0; i < 4; ++i)
#pragma unroll
          for (int j = 0; j < 4; ++j)
            acc[i][j] = __builtin_amdgcn_mfma_f32_16x16x32_bf16(af[i], bfr[j],
                                                                acc[i][j], 0, 0, 0);
      }
      __syncthreads();  // readers done before next chunk overwrites LDS
    }
    // epilogue: key = (||e||^2/2 + 1024) - z.e  (positive -> u32 bits monotone)
    const unsigned nl = (unsigned)(n0 + wn0 + l15);
#pragma unroll
    for (int i = 0; i < 4; ++i) {
#pragma unroll
      for (int r = 0; r < 4; ++r) {
        const int s = i * 4 + r;
        const u64 p0 = ((u64)__float_as_uint(eh[0] - acc[i][0][r]) << 32) | (nl);
        const u64 p1 = ((u64)__float_as_uint(eh[1] - acc[i][1][r]) << 32) | (nl + 16);
        const u64 p2 = ((u64)__float_as_uint(eh[2] - acc[i][2][r]) << 32) | (nl + 32);
        const u64 p3 = ((u64)__float_as_uint(eh[3] - acc[i][3][r]) << 32) | (nl + 48);
        // exact top-2 of 4
        const u64 lo01 = umin64(p0, p1), hi01 = umax64(p0, p1);
        const u64 lo23 = umin64(p2, p3), hi23 = umax64(p2, p3);
        const u64 best = umin64(lo01, lo23);
        const u64 sec  = umin64(umax64(lo01, lo23), umin64(hi01, hi23));
        // merge sorted pairs (best,sec) and (b1,b2)
        const u64 nb2 = umin64(umax64(best, b1[s]), umin64(sec, b2[s]));
        b1[s] = umin64(best, b1[s]);
        b2[s] = nb2;
      }
    }
  }
  // 16-lane butterfly top-2 merge within each quad group (lanes share query)
#pragma unroll
  for (int s = 0; s < 16; ++s) {
    u64 x1 = b1[s], x2 = b2[s];
#pragma unroll
    for (int off = 1; off < 16; off <<= 1) {
      const u64 o1 = __shfl_xor(x1, off, 64);
      const u64 o2 = __shfl_xor(x2, off, 64);
      const u64 lo = umin64(x1, o1);
      const u64 hi = umax64(x1, o1);
      x1 = lo;
      x2 = umin64(hi, umin64(x2, o2));
    }
    if (l15 == 0) {
      const int i = s >> 2, r = s & 3;
      const int q = q0 + wq0 + i * 16 + quad * 4 + r;
      cand[(size_t)q * 32 + split * 4 + wh * 2 + 0] = x1;  // disjoint per wave-half
      cand[(size_t)q * 32 + split * 4 + wh * 2 + 1] = x2;
    }
  }
}

// ---------------- kernel 4: top-4-of-32 select + exact fp64 rescore ----------------
__global__ __launch_bounds__(256) void k_rescore(const float* __restrict__ z,
                                                 const float* __restrict__ emb,
                                                 const u64* __restrict__ cand,
                                                 int* __restrict__ idxF) {
  const int lane = threadIdx.x & 63;
  const int w    = threadIdx.x >> 6;
  for (int it = 0; it < 16; ++it) {
    const int q = (blockIdx.x * 4 + w) * 16 + it;   // grid 256
    u64 c = cand[(size_t)q * 32 + (lane & 31)];
    u64 sel[4];
#pragma unroll
    for (int t = 0; t < 4; ++t) {
      u64 m = c;
#pragma unroll
      for (int off = 1; off < 32; off <<= 1) {
        const u64 o = __shfl_xor(m, off, 64);
        m = o < m ? o : m;
      }
      sel[t] = m;
      c = (c == m) ? ~0ull : c;
    }
    const int b = q >> 10, hw = q & 1023;
    const float* zb = z + ((size_t)(b * CD) + lane * 4) * HW + hw;
    const float z0 = zb[0], z1 = zb[HW], z2 = zb[2 * HW], z3 = zb[3 * HW];
    double bd = 1e300;
    int bi = 0x7fffffff;
#pragma unroll
    for (int t = 0; t < 4; ++t) {
      const int idx = (int)(unsigned)(sel[t] & 0xffffffffull);
      const float4 e = *(const float4*)(emb + (size_t)idx * CD + lane * 4);
      const double d0 = (double)z0 - (double)e.x;
      const double d1 = (double)z1 - (double)e.y;
      const double d2 = (double)z2 - (double)e.z;
      const double d3 = (double)z3 - (double)e.w;
      double s = d0 * d0 + d1 * d1 + d2 * d2 + d3 * d3;
#pragma unroll
      for (int off = 32; off; off >>= 1) s += __shfl_xor(s, off, 64);
      if (s < bd || (s == bd && idx < bi)) { bd = s; bi = idx; }
    }
    if (lane == 0) idxF[q] = bi;
  }
}

// ---------------- kernel 5: gather out[b][c][hw] = emb[idx][c] ----------------
__global__ __launch_bounds__(256) void k_gather(const float* __restrict__ emb,
                                                const int* __restrict__ idxF,
                                                float* __restrict__ out) {
  const int b   = blockIdx.x >> 2;             // grid 64
  const int hw0 = (blockIdx.x & 3) * 256;
  const int t   = threadIdx.x;
  const int n   = b * HW + hw0 + t;
  const int k   = idxF[n];
  const float* er = emb + (size_t)k * CD;
  float* ob = out + (size_t)b * CD * HW + hw0 + t;
#pragma unroll 2
  for (int c4 = 0; c4 < CD; c4 += 4) {
    const float4 e = *(const float4*)(er + c4);
    ob[(size_t)(c4 + 0) * HW] = e.x;
    ob[(size_t)(c4 + 1) * HW] = e.y;
    ob[(size_t)(c4 + 2) * HW] = e.z;
    ob[(size_t)(c4 + 3) * HW] = e.w;
  }
}

extern "C" void kernel_launch(void* const* d_in, const int* in_sizes, int n_in,
                              void* d_out, int out_size, void* d_ws, size_t ws_size,
                              hipStream_t stream) {
  const float* z   = (const float*)d_in[0];
  const float* emb = (const float*)d_in[1];
  float* out = (float*)d_out;

  char* ws = (char*)d_ws;
  u16*   zTb  = (u16*)(ws + ZTB_OFF);
  u16*   embB = (u16*)(ws + EMBB_OFF);
  float* eH   = (float*)(ws + EH_OFF);
  u64*   cand = (u64*)(ws + CAND_OFF);
  int*   idxF = (int*)(ws + IDX_OFF);

  k_prep_z<<<1024, 256, 0, stream>>>(z, zTb);
  k_prep_e<<<32, 256, 0, stream>>>(emb, embB, eH);
  k_argmin<<<1024, 256, 0, stream>>>(zTb, embB, eH, cand);
  k_rescore<<<256, 256, 0, stream>>>(z, emb, cand, idxF);
  k_gather<<<64, 256, 0, stream>>>(emb, idxF, out);
}

// Round 4
// 265.997 us; speedup vs baseline: 4.4243x; 1.1137x over previous
//
#include <hip/hip_runtime.h>
#include <stdint.h>

#define NB   16
#define CD   256
#define HW   1024
#define NQ   16384
#define KCN  8192

typedef unsigned long long u64;
typedef unsigned short     u16;
using f32x4  = __attribute__((ext_vector_type(4))) float;
using bf16x8 = __attribute__((ext_vector_type(8))) __bf16;

// ---------------- workspace layout (~33.7 MB) ----------------
#define ZT_OFF   0            // f32  [NQ][CD]  16 MB  (z transposed, fp32 — for exact rescore)
#define ZTB_OFF  16777216     // u16  [NQ][CD]   8 MB  (z transposed, bf16)
#define EMBB_OFF 25165824     // u16  [KCN][CD]  4 MB  (emb, bf16)
#define EH_OFF   29360128     // f32  [KCN]     32 KB  (||e||^2/2 + 1024)
#define CAND_OFF 29392896     // u64  [NQ][32]   4 MB  (8 splits x 2 wave-halves x top-2)
#define IDX_OFF  33587200     // int  [NQ]      64 KB

static __device__ __forceinline__ void gl_lds16(const void* g, void* l) {
  __builtin_amdgcn_global_load_lds(
      (const __attribute__((address_space(1))) void*)g,
      (__attribute__((address_space(3))) void*)l, 16, 0, 0);
}

static __device__ __forceinline__ unsigned bf16r(float x) {  // RNE fp32->bf16 bits
  unsigned u = __float_as_uint(x);
  return (u + 0x7fffu + ((u >> 16) & 1u)) >> 16;
}

static __device__ __forceinline__ u64 umin64(u64 a, u64 b) { return a < b ? a : b; }
static __device__ __forceinline__ u64 umax64(u64 a, u64 b) { return a < b ? b : a; }

// ---------------- kernel 1: z [b][c][hw] -> zT f32 + zTb bf16, [b*HW+hw][c] ----------------
__global__ __launch_bounds__(256) void k_prep_z(const float* __restrict__ z,
                                                float* __restrict__ zT,
                                                u16* __restrict__ zTb) {
  __shared__ float tile[64][65];
  const int bx  = blockIdx.x;          // 16 b * 16 hwT * 4 cT = 1024
  const int b   = bx >> 6;
  const int hwT = (bx >> 2) & 15;
  const int cT  = bx & 3;
  const int tx  = threadIdx.x & 63;
  const int ty  = threadIdx.x >> 6;

  const float* src = z + (size_t)(b * CD + cT * 64) * HW + hwT * 64;
#pragma unroll
  for (int i = 0; i < 16; ++i) {
    const int c_l = ty + 4 * i;
    tile[c_l][tx] = src[(size_t)c_l * HW + tx];
  }
  __syncthreads();
  const size_t dbase = (size_t)(b * HW + hwT * 64) * CD + cT * 64;
#pragma unroll
  for (int i = 0; i < 16; ++i) {
    const int hw_l = ty + 4 * i;
    const float v = tile[tx][hw_l];
    zT [dbase + (size_t)hw_l * CD + tx] = v;
    zTb[dbase + (size_t)hw_l * CD + tx] = (u16)bf16r(v);
  }
}

// ---------------- kernel 2: embB bf16 + eH = ||e||^2/2 + 1024 ----------------
__global__ __launch_bounds__(256) void k_prep_e(const float* __restrict__ emb,
                                                u16* __restrict__ embB,
                                                float* __restrict__ eH) {
  const int wave = (int)((blockIdx.x * 256 + threadIdx.x) >> 6);  // 0..127
  const int lane = threadIdx.x & 63;
  for (int it = 0; it < 64; ++it) {
    const int row = wave + it * 128;
    const float4 v = *(const float4*)(emb + (size_t)row * CD + lane * 4);
    uint2 pk;
    pk.x = bf16r(v.x) | (bf16r(v.y) << 16);
    pk.y = bf16r(v.z) | (bf16r(v.w) << 16);
    *(uint2*)(embB + (size_t)row * CD + lane * 4) = pk;
    float s = v.x * v.x + v.y * v.y + v.z * v.z + v.w * v.w;
#pragma unroll
    for (int off = 32; off; off >>= 1) s += __shfl_xor(s, off, 64);
    if (lane == 0) eH[row] = 0.5f * s + 1024.0f;
  }
}

// ---------------- kernel 3: MFMA GEMM + fused top-2 argmin ----------------
// grid = 128 q-tiles * 8 splits; block 256 = 4 waves; wave w: queries (w&1)*64..+64,
// codes (w>>1)*64..+64. K=256 in 4 chunks of BK=64.
// LDS tiles [128 rows][64 bf16], XOR-SWIZZLED: logical 16B-chunk c of row r stored at
// physical chunk c^(r&7). Staging stays flat (global_load_lds wave-uniform constraint);
// the swizzle is folded into the GLOBAL source chunk. Frag ds_read_b128 banks become
// ((ks*4+quad)^(lane&7))*4 -> each 4-bank group hit by exactly 2 lanes = free (m136).
#define NT  8
#define BKC 4

__global__ __launch_bounds__(256, 2) void k_argmin(const u16* __restrict__ zTb,
                                                   const u16* __restrict__ embB,
                                                   const float* __restrict__ eH,
                                                   u64* __restrict__ cand) {
  __shared__ __align__(16) u16 As[128 * 64];
  __shared__ __align__(16) u16 Bs[128 * 64];
  const int tid  = threadIdx.x;
  const int w    = tid >> 6;
  const int lane = tid & 63;
  const int l15  = lane & 15, quad = lane >> 4, l7 = lane & 7;
  const int q0    = (blockIdx.x >> 3) * 128;
  const int split = blockIdx.x & 7;
  const int wq0 = (w & 1) * 64, wn0 = (w >> 1) * 64, wh = w >> 1;

  // staging: wave w fills physical rows [w*32, w*32+32); lane -> phys chunk lane&7,
  // phys row offset lane>>3; logical source chunk = (lane&7) ^ (lane>>3)  (row&7 == lane>>3)
  const int srow  = w * 32 + (lane >> 3);          // + i*8
  const int scol8 = (l7 ^ (lane >> 3)) * 8;        // logical chunk * 8 elements
  const int ldsL  = w * 4096 + lane * 16;          // byte offset, + i*1024

  // frag reads: row = wq0+i*16+l15 (row&7 == l7), logical chunk = ks*4+quad
  const int co0 = ((0 * 4 + quad) ^ l7) * 16;      // ks=0 byte offset within row
  const int co1 = ((1 * 4 + quad) ^ l7) * 16;      // ks=1

  u64 b1[16], b2[16];
#pragma unroll
  for (int s = 0; s < 16; ++s) { b1[s] = ~0ull; b2[s] = ~0ull; }

  for (int nt = 0; nt < NT; ++nt) {
    const int n0 = split * 1024 + nt * 128;
    float eh[4];
#pragma unroll
    for (int j = 0; j < 4; ++j) eh[j] = eH[n0 + wn0 + 16 * j + l15];

    f32x4 acc[4][4];
#pragma unroll
    for (int i = 0; i < 4; ++i)
#pragma unroll
      for (int j = 0; j < 4; ++j) acc[i][j] = f32x4{0.f, 0.f, 0.f, 0.f};

    for (int kc = 0; kc < BKC; ++kc) {
#pragma unroll
      for (int i = 0; i < 4; ++i) {
        const int row = srow + i * 8;
        gl_lds16(zTb  + (size_t)(q0 + row) * CD + kc * 64 + scol8,
                 (char*)As + ldsL + i * 1024);
        gl_lds16(embB + (size_t)(n0 + row) * CD + kc * 64 + scol8,
                 (char*)Bs + ldsL + i * 1024);
      }
      __syncthreads();  // drains vmcnt (async LDS writes visible)
#pragma unroll
      for (int ks = 0; ks < 2; ++ks) {
        const int co = ks ? co1 : co0;
        bf16x8 af[4], bfr[4];
#pragma unroll
        for (int i = 0; i < 4; ++i)
          af[i] = *(const bf16x8*)((const char*)As + (wq0 + i * 16 + l15) * 128 + co);
#pragma unroll
        for (int j = 0; j < 4; ++j)
          bfr[j] = *(const bf16x8*)((const char*)Bs + (wn0 + j * 16 + l15) * 128 + co);
#pragma unroll
        for (int i = 0; i < 4; ++i)
#pragma unroll
          for (int j = 0; j < 4; ++j)
            acc[i][j] = __builtin_amdgcn_mfma_f32_16x16x32_bf16(af[i], bfr[j],
                                                                acc[i][j], 0, 0, 0);
      }
      __syncthreads();  // readers done before next chunk overwrites LDS
    }
    // epilogue: key = (||e||^2/2 + 1024) - z.e  (positive -> u32 bits monotone)
    const unsigned nl = (unsigned)(n0 + wn0 + l15);
#pragma unroll
    for (int i = 0; i < 4; ++i) {
#pragma unroll
      for (int r = 0; r < 4; ++r) {
        const int s = i * 4 + r;
        const u64 p0 = ((u64)__float_as_uint(eh[0] - acc[i][0][r]) << 32) | (nl);
        const u64 p1 = ((u64)__float_as_uint(eh[1] - acc[i][1][r]) << 32) | (nl + 16);
        const u64 p2 = ((u64)__float_as_uint(eh[2] - acc[i][2][r]) << 32) | (nl + 32);
        const u64 p3 = ((u64)__float_as_uint(eh[3] - acc[i][3][r]) << 32) | (nl + 48);
        const u64 lo01 = umin64(p0, p1), hi01 = umax64(p0, p1);
        const u64 lo23 = umin64(p2, p3), hi23 = umax64(p2, p3);
        const u64 best = umin64(lo01, lo23);
        const u64 sec  = umin64(umax64(lo01, lo23), umin64(hi01, hi23));
        const u64 nb2  = umin64(umax64(best, b1[s]), umin64(sec, b2[s]));
        b1[s] = umin64(best, b1[s]);
        b2[s] = nb2;
      }
    }
  }
  // 16-lane butterfly top-2 merge (lanes of one quad share a query)
#pragma unroll
  for (int s = 0; s < 16; ++s) {
    u64 x1 = b1[s], x2 = b2[s];
#pragma unroll
    for (int off = 1; off < 16; off <<= 1) {
      const u64 o1 = __shfl_xor(x1, off, 64);
      const u64 o2 = __shfl_xor(x2, off, 64);
      const u64 lo = umin64(x1, o1);
      const u64 hi = umax64(x1, o1);
      x1 = lo;
      x2 = umin64(hi, umin64(x2, o2));
    }
    if (l15 == 0) {
      const int i = s >> 2, r = s & 3;
      const int q = q0 + wq0 + i * 16 + quad * 4 + r;
      cand[(size_t)q * 32 + split * 4 + wh * 2 + 0] = x1;  // disjoint per wave-half
      cand[(size_t)q * 32 + split * 4 + wh * 2 + 1] = x2;
    }
  }
}

// ---------------- kernel 4: top-4-of-32 select + exact fp64 rescore (reads fp32 zT) ----------------
__global__ __launch_bounds__(256) void k_rescore(const float* __restrict__ zT,
                                                 const float* __restrict__ emb,
                                                 const u64* __restrict__ cand,
                                                 int* __restrict__ idxF) {
  const int lane = threadIdx.x & 63;
  const int w    = threadIdx.x >> 6;
  for (int it = 0; it < 16; ++it) {
    const int q = (blockIdx.x * 4 + w) * 16 + it;   // grid 256
    u64 c = cand[(size_t)q * 32 + (lane & 31)];
    u64 sel[4];
#pragma unroll
    for (int t = 0; t < 4; ++t) {
      u64 m = c;
#pragma unroll
      for (int off = 1; off < 32; off <<= 1) {
        const u64 o = __shfl_xor(m, off, 64);
        m = o < m ? o : m;
      }
      sel[t] = m;
      c = (c == m) ? ~0ull : c;
    }
    const float4 zv = *(const float4*)(zT + (size_t)q * CD + lane * 4);  // coalesced
    double bd = 1e300;
    int bi = 0x7fffffff;
#pragma unroll
    for (int t = 0; t < 4; ++t) {
      const int idx = (int)(unsigned)(sel[t] & 0xffffffffull);
      const float4 e = *(const float4*)(emb + (size_t)idx * CD + lane * 4);
      const double d0 = (double)zv.x - (double)e.x;
      const double d1 = (double)zv.y - (double)e.y;
      const double d2 = (double)zv.z - (double)e.z;
      const double d3 = (double)zv.w - (double)e.w;
      double s = d0 * d0 + d1 * d1 + d2 * d2 + d3 * d3;
#pragma unroll
      for (int off = 32; off; off >>= 1) s += __shfl_xor(s, off, 64);
      if (s < bd || (s == bd && idx < bi)) { bd = s; bi = idx; }
    }
    if (lane == 0) idxF[q] = bi;
  }
}

// ---------------- kernel 5: gather out[b][c][hw] = emb[idx][c] ----------------
__global__ __launch_bounds__(256) void k_gather(const float* __restrict__ emb,
                                                const int* __restrict__ idxF,
                                                float* __restrict__ out) {
  const int b   = blockIdx.x >> 2;             // grid 64
  const int hw0 = (blockIdx.x & 3) * 256;
  const int t   = threadIdx.x;
  const int n   = b * HW + hw0 + t;
  const int k   = idxF[n];
  const float* er = emb + (size_t)k * CD;
  float* ob = out + (size_t)b * CD * HW + hw0 + t;
#pragma unroll 2
  for (int c4 = 0; c4 < CD; c4 += 4) {
    const float4 e = *(const float4*)(er + c4);
    ob[(size_t)(c4 + 0) * HW] = e.x;
    ob[(size_t)(c4 + 1) * HW] = e.y;
    ob[(size_t)(c4 + 2) * HW] = e.z;
    ob[(size_t)(c4 + 3) * HW] = e.w;
  }
}

extern "C" void kernel_launch(void* const* d_in, const int* in_sizes, int n_in,
                              void* d_out, int out_size, void* d_ws, size_t ws_size,
                              hipStream_t stream) {
  const float* z   = (const float*)d_in[0];
  const float* emb = (const float*)d_in[1];
  float* out = (float*)d_out;

  char* ws = (char*)d_ws;
  float* zT   = (float*)(ws + ZT_OFF);
  u16*   zTb  = (u16*)(ws + ZTB_OFF);
  u16*   embB = (u16*)(ws + EMBB_OFF);
  float* eH   = (float*)(ws + EH_OFF);
  u64*   cand = (u64*)(ws + CAND_OFF);
  int*   idxF = (int*)(ws + IDX_OFF);

  k_prep_z<<<1024, 256, 0, stream>>>(z, zT, zTb);
  k_prep_e<<<32, 256, 0, stream>>>(emb, embB, eH);
  k_argmin<<<1024, 256, 0, stream>>>(zTb, embB, eH, cand);
  k_rescore<<<256, 256, 0, stream>>>(zT, emb, cand, idxF);
  k_gather<<<64, 256, 0, stream>>>(emb, idxF, out);
}

// Round 5
// 242.366 us; speedup vs baseline: 4.8557x; 1.0975x over previous
//
#include <hip/hip_runtime.h>
#include <stdint.h>

#define NB   16
#define CD   256
#define HW   1024
#define NQ   16384
#define KCN  8192

typedef unsigned long long u64;
typedef unsigned short     u16;
using f32x4  = __attribute__((ext_vector_type(4))) float;
using bf16x8 = __attribute__((ext_vector_type(8))) __bf16;

// ---------------- workspace layout (~46.2 MB) ----------------
#define ZT_OFF   0            // f32  [NQ][CD]   16 MB  (z transposed, fp32)
#define ZTB_OFF  16777216     // u16  [NQ][CD]    8 MB  (z transposed, bf16)
#define EMBB_OFF 25165824     // u16  [KCN][CD]   4 MB  (emb, bf16)
#define EH_OFF   29360128     // f32  [KCN]      32 KB  (||e||^2/2 + 1024)
#define CAND_OFF 29392896     // u64  [NQ][128]  16 MB  (32 nblks x 2 halves x top-2)
#define IDX_OFF  46170112     // int  [NQ]       64 KB

static __device__ __forceinline__ void gl_lds16(const void* g, void* l) {
  __builtin_amdgcn_global_load_lds(
      (const __attribute__((address_space(1))) void*)g,
      (__attribute__((address_space(3))) void*)l, 16, 0, 0);
}

static __device__ __forceinline__ unsigned bf16r(float x) {  // RNE fp32->bf16 bits
  unsigned u = __float_as_uint(x);
  return (u + 0x7fffu + ((u >> 16) & 1u)) >> 16;
}

static __device__ __forceinline__ u64 umin64(u64 a, u64 b) { return a < b ? a : b; }
static __device__ __forceinline__ u64 umax64(u64 a, u64 b) { return a < b ? b : a; }

// ---------------- kernel 1: z [b][c][hw] -> zT f32 + zTb bf16, [b*HW+hw][c] ----------------
__global__ __launch_bounds__(256) void k_prep_z(const float* __restrict__ z,
                                                float* __restrict__ zT,
                                                u16* __restrict__ zTb) {
  __shared__ float tile[64][65];
  const int bx  = blockIdx.x;          // 16 b * 16 hwT * 4 cT = 1024
  const int b   = bx >> 6;
  const int hwT = (bx >> 2) & 15;
  const int cT  = bx & 3;
  const int tx  = threadIdx.x & 63;
  const int ty  = threadIdx.x >> 6;

  const float* src = z + (size_t)(b * CD + cT * 64) * HW + hwT * 64;
#pragma unroll
  for (int i = 0; i < 16; ++i) {
    const int c_l = ty + 4 * i;
    tile[c_l][tx] = src[(size_t)c_l * HW + tx];
  }
  __syncthreads();
  const size_t dbase = (size_t)(b * HW + hwT * 64) * CD + cT * 64;
#pragma unroll
  for (int i = 0; i < 16; ++i) {
    const int hw_l = ty + 4 * i;
    const float v = tile[tx][hw_l];
    zT [dbase + (size_t)hw_l * CD + tx] = v;
    zTb[dbase + (size_t)hw_l * CD + tx] = (u16)bf16r(v);
  }
}

// ---------------- kernel 2: embB bf16 + eH = ||e||^2/2 + 1024 (grid 256) ----------------
__global__ __launch_bounds__(256) void k_prep_e(const float* __restrict__ emb,
                                                u16* __restrict__ embB,
                                                float* __restrict__ eH) {
  const int wave = (int)(blockIdx.x * 4 + (threadIdx.x >> 6));  // 0..1023
  const int lane = threadIdx.x & 63;
#pragma unroll
  for (int it = 0; it < 8; ++it) {
    const int row = wave * 8 + it;
    const float4 v = *(const float4*)(emb + (size_t)row * CD + lane * 4);
    uint2 pk;
    pk.x = bf16r(v.x) | (bf16r(v.y) << 16);
    pk.y = bf16r(v.z) | (bf16r(v.w) << 16);
    *(uint2*)(embB + (size_t)row * CD + lane * 4) = pk;
    float s = v.x * v.x + v.y * v.y + v.z * v.z + v.w * v.w;
#pragma unroll
    for (int off = 32; off; off >>= 1) s += __shfl_xor(s, off, 64);
    if (lane == 0) eH[row] = 0.5f * s + 1024.0f;
  }
}

// ---------------- kernel 3: MFMA GEMM + fused top-2 argmin ----------------
// grid = 128 q-tiles * 32 n-blocks = 4096. Block tile 128q x 256n, K=256 in 4 chunks
// of BK=64. 4 waves: wave w covers queries (w&1)*64..+64, codes (w>>1)*128..+128
// (wave tile 64x128, acc 4x8 f32x4 = 128 VGPR). No nt loop: one n-tile per block,
// epilogue runs once (b1/b2 are transients). LDS: As 16KB + Bs 32KB, XOR-swizzled
// (logical 16B chunk c of row r at phys c^(r&7)) -> frag reads 2-way = free (R4: 0 conflicts).
__global__ __launch_bounds__(256, 2) void k_argmin(const u16* __restrict__ zTb,
                                                   const u16* __restrict__ embB,
                                                   const float* __restrict__ eH,
                                                   u64* __restrict__ cand) {
  __shared__ __align__(16) u16 As[128 * 64];   // 16 KB
  __shared__ __align__(16) u16 Bs[256 * 64];   // 32 KB
  const int tid  = threadIdx.x;
  const int w    = tid >> 6;
  const int lane = tid & 63;
  const int l15  = lane & 15, quad = lane >> 4, l7 = lane & 7;
  const int q0   = (int)(blockIdx.x >> 5) * 128;
  const int nblk = (int)(blockIdx.x & 31);
  const int n0   = nblk * 256;
  const int wq0 = (w & 1) * 64, wn0 = (w >> 1) * 128, wh = w >> 1;

  // staging maps (global_load_lds: wave-uniform base + lane*16)
  const int srowA = w * 32 + (lane >> 3);          // + i*8, i<4
  const int srowB = w * 64 + (lane >> 3);          // + i*8, i<8
  const int scol8 = (l7 ^ (lane >> 3)) * 8;        // logical chunk * 8 elems
  const int ldsA  = w * 4096 + lane * 16;          // + i*1024
  const int ldsB  = w * 8192 + lane * 16;          // + i*1024
  // frag-read swizzled byte offsets within a row (row&7 == l7)
  const int co0 = ((0 * 4 + quad) ^ l7) * 16;
  const int co1 = ((1 * 4 + quad) ^ l7) * 16;

  float eh[8];
#pragma unroll
  for (int j = 0; j < 8; ++j) eh[j] = eH[n0 + wn0 + 16 * j + l15];

  f32x4 acc[4][8];
#pragma unroll
  for (int i = 0; i < 4; ++i)
#pragma unroll
    for (int j = 0; j < 8; ++j) acc[i][j] = f32x4{0.f, 0.f, 0.f, 0.f};

  for (int kc = 0; kc < 4; ++kc) {
#pragma unroll
    for (int i = 0; i < 4; ++i)
      gl_lds16(zTb + (size_t)(q0 + srowA + i * 8) * CD + kc * 64 + scol8,
               (char*)As + ldsA + i * 1024);
#pragma unroll
    for (int i = 0; i < 8; ++i)
      gl_lds16(embB + (size_t)(n0 + srowB + i * 8) * CD + kc * 64 + scol8,
               (char*)Bs + ldsB + i * 1024);
    __syncthreads();
#pragma unroll
    for (int ks = 0; ks < 2; ++ks) {
      const int co = ks ? co1 : co0;
      bf16x8 af[4], bfr[8];
#pragma unroll
      for (int i = 0; i < 4; ++i)
        af[i] = *(const bf16x8*)((const char*)As + (wq0 + i * 16 + l15) * 128 + co);
#pragma unroll
      for (int j = 0; j < 8; ++j)
        bfr[j] = *(const bf16x8*)((const char*)Bs + (wn0 + j * 16 + l15) * 128 + co);
#pragma unroll
      for (int i = 0; i < 4; ++i)
#pragma unroll
        for (int j = 0; j < 8; ++j)
          acc[i][j] = __builtin_amdgcn_mfma_f32_16x16x32_bf16(af[i], bfr[j],
                                                              acc[i][j], 0, 0, 0);
    }
    __syncthreads();
  }

  // ---- epilogue (once): key = (||e||^2/2 + 1024) - z.e ; top-2 of 8 cols, merge, write
  const unsigned nl = (unsigned)(n0 + wn0 + l15);
#pragma unroll
  for (int i = 0; i < 4; ++i) {
#pragma unroll
    for (int r = 0; r < 4; ++r) {
      u64 p[8];
#pragma unroll
      for (int j = 0; j < 8; ++j)
        p[j] = ((u64)__float_as_uint(eh[j] - acc[i][j][r]) << 32) | (nl + 16 * j);
      // sorted pairs
      const u64 lo0 = umin64(p[0], p[1]), hi0 = umax64(p[0], p[1]);
      const u64 lo1 = umin64(p[2], p[3]), hi1 = umax64(p[2], p[3]);
      const u64 lo2 = umin64(p[4], p[5]), hi2 = umax64(p[4], p[5]);
      const u64 lo3 = umin64(p[6], p[7]), hi3 = umax64(p[6], p[7]);
      // top2 of (lo0,hi0)x(lo1,hi1) and (lo2,hi2)x(lo3,hi3)
      const u64 qa1 = umin64(lo0, lo1);
      const u64 qa2 = umin64(umax64(lo0, lo1), umin64(hi0, hi1));
      const u64 qb1 = umin64(lo2, lo3);
      const u64 qb2 = umin64(umax64(lo2, lo3), umin64(hi2, hi3));
      // combine
      u64 b1 = umin64(qa1, qb1);
      u64 b2 = umin64(umax64(qa1, qb1), umin64(qa2, qb2));
      // 16-lane butterfly top-2 merge (lanes of a quad group share a query)
#pragma unroll
      for (int off = 1; off < 16; off <<= 1) {
        const u64 o1 = __shfl_xor(b1, off, 64);
        const u64 o2 = __shfl_xor(b2, off, 64);
        const u64 lo = umin64(b1, o1);
        const u64 hi = umax64(b1, o1);
        b1 = lo;
        b2 = umin64(hi, umin64(b2, o2));
      }
      if (l15 == 0) {
        const int q = q0 + wq0 + i * 16 + quad * 4 + r;
        cand[(size_t)q * 128 + nblk * 4 + wh * 2 + 0] = b1;
        cand[(size_t)q * 128 + nblk * 4 + wh * 2 + 1] = b2;
      }
    }
  }
}

// ---------------- kernel 4: fused top-4-of-128 select + exact fp64 rescore ----------------
// 16 lanes per query (4 queries/wave, grid 1024): local top-4 of 8 slots, butterfly
// sorted-4 merge over 16 lanes, then fp64 rescore of the 4 survivors (lane c-slices).
__global__ __launch_bounds__(256) void k_pick(const float* __restrict__ zT,
                                              const float* __restrict__ emb,
                                              const u64* __restrict__ cand,
                                              int* __restrict__ idxF) {
  const int lane = threadIdx.x & 63;
  const int wv   = threadIdx.x >> 6;
  const int sub  = lane >> 4;         // query within wave
  const int l15  = lane & 15;
  const int q = (int)(blockIdx.x * 16) + wv * 4 + sub;

  // local sorted top-4 (ascending) of my 8 slots
  u64 s0 = ~0ull, s1 = ~0ull, s2 = ~0ull, s3 = ~0ull;
  const u64* cp = cand + (size_t)q * 128 + l15 * 8;
#pragma unroll
  for (int j = 0; j < 8; ++j) {
    u64 v = cp[j];
    const u64 t0 = umin64(s0, v); v = umax64(s0, v); s0 = t0;
    const u64 t1 = umin64(s1, v); v = umax64(s1, v); s1 = t1;
    const u64 t2 = umin64(s2, v); v = umax64(s2, v); s2 = t2;
    s3 = umin64(s3, v);
  }
  // butterfly merge of sorted-4 lists over the 16-lane group
#pragma unroll
  for (int off = 1; off < 16; off <<= 1) {
    const u64 b0 = __shfl_xor(s0, off, 64);
    const u64 b1 = __shfl_xor(s1, off, 64);
    const u64 b2 = __shfl_xor(s2, off, 64);
    const u64 b3 = __shfl_xor(s3, off, 64);
    const u64 c0 = umin64(s0, b0);
    const u64 c1 = umin64(umin64(s1, b1), umax64(s0, b0));
    const u64 c2 = umin64(umin64(s2, b2),
                          umin64(umax64(s1, b0), umax64(s0, b1)));
    const u64 c3 = umin64(umin64(umin64(s3, b3), umax64(s2, b0)),
                          umin64(umax64(s0, b2), umax64(s1, b1)));
    s0 = c0; s1 = c1; s2 = c2; s3 = c3;
  }
  const u64 sel[4] = {s0, s1, s2, s3};

  // fp64 rescore: lane slice = 16 channels
  const float* zrow = zT + (size_t)q * CD + l15 * 16;
  const float4 za = *(const float4*)(zrow + 0);
  const float4 zb = *(const float4*)(zrow + 4);
  const float4 zc = *(const float4*)(zrow + 8);
  const float4 zd = *(const float4*)(zrow + 12);
  double bd = 1e300;
  int bi = 0x7fffffff;
#pragma unroll
  for (int t = 0; t < 4; ++t) {
    const int idx = (int)(unsigned)(sel[t] & 0xffffffffull);
    const float* er = emb + (size_t)idx * CD + l15 * 16;
    const float4 ea = *(const float4*)(er + 0);
    const float4 eb = *(const float4*)(er + 4);
    const float4 ec = *(const float4*)(er + 8);
    const float4 ed = *(const float4*)(er + 12);
    double s = 0.0;
#define ACC1(zv, ev) { const double d = (double)(zv) - (double)(ev); s += d * d; }
    ACC1(za.x, ea.x) ACC1(za.y, ea.y) ACC1(za.z, ea.z) ACC1(za.w, ea.w)
    ACC1(zb.x, eb.x) ACC1(zb.y, eb.y) ACC1(zb.z, eb.z) ACC1(zb.w, eb.w)
    ACC1(zc.x, ec.x) ACC1(zc.y, ec.y) ACC1(zc.z, ec.z) ACC1(zc.w, ec.w)
    ACC1(zd.x, ed.x) ACC1(zd.y, ed.y) ACC1(zd.z, ed.z) ACC1(zd.w, ed.w)
#undef ACC1
#pragma unroll
    for (int off = 1; off < 16; off <<= 1) s += __shfl_xor(s, off, 64);
    if (s < bd || (s == bd && idx < bi)) { bd = s; bi = idx; }
  }
  if (l15 == 0) idxF[q] = bi;
}

// ---------------- kernel 5: gather out[b][c][hw] = emb[idx][c] (grid 256) ----------------
__global__ __launch_bounds__(256) void k_gather(const float* __restrict__ emb,
                                                const int* __restrict__ idxF,
                                                float* __restrict__ out) {
  const int b   = (int)(blockIdx.x >> 4);        // 16
  const int hw0 = (int)(blockIdx.x & 15) * 64;
  const int lane = threadIdx.x & 63;
  const int cg   = threadIdx.x >> 6;             // 0..3 -> c block of 64
  const int hw = hw0 + lane;
  const int k  = idxF[b * HW + hw];
  const float* er = emb + (size_t)k * CD + cg * 64;
  float* ob = out + (size_t)b * CD * HW + (size_t)(cg * 64) * HW + hw;
#pragma unroll
  for (int j = 0; j < 16; ++j) {
    const float4 e = *(const float4*)(er + j * 4);
    ob[(size_t)(j * 4 + 0) * HW] = e.x;   // lanes cover consecutive hw: coalesced
    ob[(size_t)(j * 4 + 1) * HW] = e.y;
    ob[(size_t)(j * 4 + 2) * HW] = e.z;
    ob[(size_t)(j * 4 + 3) * HW] = e.w;
  }
}

extern "C" void kernel_launch(void* const* d_in, const int* in_sizes, int n_in,
                              void* d_out, int out_size, void* d_ws, size_t ws_size,
                              hipStream_t stream) {
  const float* z   = (const float*)d_in[0];
  const float* emb = (const float*)d_in[1];
  float* out = (float*)d_out;

  char* ws = (char*)d_ws;
  float* zT   = (float*)(ws + ZT_OFF);
  u16*   zTb  = (u16*)(ws + ZTB_OFF);
  u16*   embB = (u16*)(ws + EMBB_OFF);
  float* eH   = (float*)(ws + EH_OFF);
  u64*   cand = (u64*)(ws + CAND_OFF);
  int*   idxF = (int*)(ws + IDX_OFF);

  k_prep_z<<<1024, 256, 0, stream>>>(z, zT, zTb);
  k_prep_e<<<256, 256, 0, stream>>>(emb, embB, eH);
  k_argmin<<<4096, 256, 0, stream>>>(zTb, embB, eH, cand);
  k_pick<<<1024, 256, 0, stream>>>(zT, emb, cand, idxF);
  k_gather<<<256, 256, 0, stream>>>(emb, idxF, out);
}

// Round 6
// 203.146 us; speedup vs baseline: 5.7931x; 1.1931x over previous
//
#include <hip/hip_runtime.h>
#include <stdint.h>

#define NB   16
#define CD   256
#define HW   1024
#define NQ   16384
#define KCN  8192

typedef unsigned long long u64;
typedef unsigned short     u16;
using f32x4  = __attribute__((ext_vector_type(4))) float;
using bf16x8 = __attribute__((ext_vector_type(8))) __bf16;

// ---------------- workspace layout (~37.8 MB) ----------------
#define ZT_OFF   0            // f32  [NQ][CD]   16 MB  (z transposed, fp32)
#define ZTB_OFF  16777216     // u16  [NQ][CD]    8 MB  (z transposed, bf16)
#define EMBB_OFF 25165824     // u16  [KCN][CD]   4 MB  (emb, bf16)
#define EH_OFF   29360128     // f32  [KCN]      32 KB  (||e||^2/2 + 1024)
#define CAND_OFF 29392896     // u64  [NQ][64]    8 MB  (16 splits x 2 halves x top-2)
#define IDX_OFF  37781504     // int  [NQ]       64 KB

static __device__ __forceinline__ void gl_lds16(const void* g, void* l) {
  __builtin_amdgcn_global_load_lds(
      (const __attribute__((address_space(1))) void*)g,
      (__attribute__((address_space(3))) void*)l, 16, 0, 0);
}

static __device__ __forceinline__ unsigned bf16r(float x) {  // RNE fp32->bf16 bits
  unsigned u = __float_as_uint(x);
  return (u + 0x7fffu + ((u >> 16) & 1u)) >> 16;
}

static __device__ __forceinline__ u64 umin64(u64 a, u64 b) { return a < b ? a : b; }
static __device__ __forceinline__ u64 umax64(u64 a, u64 b) { return a < b ? b : a; }

// ---------------- kernel 1: merged prep ----------------
// blocks [0,1024): z [b][c][hw] -> zT f32 + zTb bf16, [b*HW+hw][c]
// blocks [1024,1280): embB bf16 + eH = ||e||^2/2 + 1024
__global__ __launch_bounds__(256) void k_prep(const float* __restrict__ z,
                                              const float* __restrict__ emb,
                                              float* __restrict__ zT,
                                              u16* __restrict__ zTb,
                                              u16* __restrict__ embB,
                                              float* __restrict__ eH) {
  const int bx = (int)blockIdx.x;
  if (bx < 1024) {
    __shared__ float tile[64][65];
    const int b   = bx >> 6;
    const int hwT = (bx >> 2) & 15;
    const int cT  = bx & 3;
    const int tx  = threadIdx.x & 63;
    const int ty  = threadIdx.x >> 6;
    const float* src = z + (size_t)(b * CD + cT * 64) * HW + hwT * 64;
#pragma unroll
    for (int i = 0; i < 16; ++i) {
      const int c_l = ty + 4 * i;
      tile[c_l][tx] = src[(size_t)c_l * HW + tx];
    }
    __syncthreads();
    const size_t dbase = (size_t)(b * HW + hwT * 64) * CD + cT * 64;
#pragma unroll
    for (int i = 0; i < 16; ++i) {
      const int hw_l = ty + 4 * i;
      const float v = tile[tx][hw_l];
      zT [dbase + (size_t)hw_l * CD + tx] = v;
      zTb[dbase + (size_t)hw_l * CD + tx] = (u16)bf16r(v);
    }
  } else {
    const int wave = (bx - 1024) * 4 + ((int)threadIdx.x >> 6);  // 0..1023
    const int lane = threadIdx.x & 63;
#pragma unroll
    for (int it = 0; it < 8; ++it) {
      const int row = wave * 8 + it;
      const float4 v = *(const float4*)(emb + (size_t)row * CD + lane * 4);
      uint2 pk;
      pk.x = bf16r(v.x) | (bf16r(v.y) << 16);
      pk.y = bf16r(v.z) | (bf16r(v.w) << 16);
      *(uint2*)(embB + (size_t)row * CD + lane * 4) = pk;
      float s = v.x * v.x + v.y * v.y + v.z * v.z + v.w * v.w;
#pragma unroll
      for (int off = 32; off; off >>= 1) s += __shfl_xor(s, off, 64);
      if (lane == 0) eH[row] = 0.5f * s + 1024.0f;
    }
  }
}

// ---------------- kernel 2: MFMA GEMM + fused top-2 argmin (R4 tile, 16 splits) ----------------
// grid = 128 q-tiles * 16 splits = 2048; block 256 = 4 waves; wave w: queries
// (w&1)*64..+64, codes (w>>1)*64..+64 of the 128x128 tile. SPLITK=512 -> NT=4
// n-tiles per block; K=256 in 4 chunks of BK=64. LDS [128][64] bf16 per operand,
// XOR-swizzled (chunk c of row r at phys c^(r&7)): frag reads 2-way = free (R4: 0 conflicts).
// Wave-halves (w>>1) cover disjoint codes -> disjoint cand slots (race-free).
#define NT  4
#define BKC 4

__global__ __launch_bounds__(256, 2) void k_argmin(const u16* __restrict__ zTb,
                                                   const u16* __restrict__ embB,
                                                   const float* __restrict__ eH,
                                                   u64* __restrict__ cand) {
  __shared__ __align__(16) u16 As[128 * 64];
  __shared__ __align__(16) u16 Bs[128 * 64];
  const int tid  = threadIdx.x;
  const int w    = tid >> 6;
  const int lane = tid & 63;
  const int l15  = lane & 15, quad = lane >> 4, l7 = lane & 7;
  const int q0    = (int)(blockIdx.x >> 4) * 128;
  const int split = (int)(blockIdx.x & 15);
  const int wq0 = (w & 1) * 64, wn0 = (w >> 1) * 64, wh = w >> 1;

  const int srow  = w * 32 + (lane >> 3);          // + i*8
  const int scol8 = (l7 ^ (lane >> 3)) * 8;        // logical chunk * 8 elems
  const int ldsL  = w * 4096 + lane * 16;          // byte offset, + i*1024
  const int co0 = ((0 * 4 + quad) ^ l7) * 16;      // frag-read swizzled byte offsets
  const int co1 = ((1 * 4 + quad) ^ l7) * 16;

  u64 b1[16], b2[16];
#pragma unroll
  for (int s = 0; s < 16; ++s) { b1[s] = ~0ull; b2[s] = ~0ull; }

  for (int nt = 0; nt < NT; ++nt) {
    const int n0 = split * 512 + nt * 128;
    float eh[4];
#pragma unroll
    for (int j = 0; j < 4; ++j) eh[j] = eH[n0 + wn0 + 16 * j + l15];

    f32x4 acc[4][4];
#pragma unroll
    for (int i = 0; i < 4; ++i)
#pragma unroll
      for (int j = 0; j < 4; ++j) acc[i][j] = f32x4{0.f, 0.f, 0.f, 0.f};

    for (int kc = 0; kc < BKC; ++kc) {
#pragma unroll
      for (int i = 0; i < 4; ++i) {
        const int row = srow + i * 8;
        gl_lds16(zTb  + (size_t)(q0 + row) * CD + kc * 64 + scol8,
                 (char*)As + ldsL + i * 1024);
        gl_lds16(embB + (size_t)(n0 + row) * CD + kc * 64 + scol8,
                 (char*)Bs + ldsL + i * 1024);
      }
      __syncthreads();
#pragma unroll
      for (int ks = 0; ks < 2; ++ks) {
        const int co = ks ? co1 : co0;
        bf16x8 af[4], bfr[4];
#pragma unroll
        for (int i = 0; i < 4; ++i)
          af[i] = *(const bf16x8*)((const char*)As + (wq0 + i * 16 + l15) * 128 + co);
#pragma unroll
        for (int j = 0; j < 4; ++j)
          bfr[j] = *(const bf16x8*)((const char*)Bs + (wn0 + j * 16 + l15) * 128 + co);
#pragma unroll
        for (int i = 0; i < 4; ++i)
#pragma unroll
          for (int j = 0; j < 4; ++j)
            acc[i][j] = __builtin_amdgcn_mfma_f32_16x16x32_bf16(af[i], bfr[j],
                                                                acc[i][j], 0, 0, 0);
      }
      __syncthreads();
    }
    // epilogue: key = (||e||^2/2 + 1024) - z.e  (positive -> u32 bits monotone)
    const unsigned nl = (unsigned)(n0 + wn0 + l15);
#pragma unroll
    for (int i = 0; i < 4; ++i) {
#pragma unroll
      for (int r = 0; r < 4; ++r) {
        const int s = i * 4 + r;
        const u64 p0 = ((u64)__float_as_uint(eh[0] - acc[i][0][r]) << 32) | (nl);
        const u64 p1 = ((u64)__float_as_uint(eh[1] - acc[i][1][r]) << 32) | (nl + 16);
        const u64 p2 = ((u64)__float_as_uint(eh[2] - acc[i][2][r]) << 32) | (nl + 32);
        const u64 p3 = ((u64)__float_as_uint(eh[3] - acc[i][3][r]) << 32) | (nl + 48);
        const u64 lo01 = umin64(p0, p1), hi01 = umax64(p0, p1);
        const u64 lo23 = umin64(p2, p3), hi23 = umax64(p2, p3);
        const u64 best = umin64(lo01, lo23);
        const u64 sec  = umin64(umax64(lo01, lo23), umin64(hi01, hi23));
        const u64 nb2  = umin64(umax64(best, b1[s]), umin64(sec, b2[s]));
        b1[s] = umin64(best, b1[s]);
        b2[s] = nb2;
      }
    }
  }
  // 16-lane butterfly top-2 merge (lanes of a quad group share a query)
#pragma unroll
  for (int s = 0; s < 16; ++s) {
    u64 x1 = b1[s], x2 = b2[s];
#pragma unroll
    for (int off = 1; off < 16; off <<= 1) {
      const u64 o1 = __shfl_xor(x1, off, 64);
      const u64 o2 = __shfl_xor(x2, off, 64);
      const u64 lo = umin64(x1, o1);
      const u64 hi = umax64(x1, o1);
      x1 = lo;
      x2 = umin64(hi, umin64(x2, o2));
    }
    if (l15 == 0) {
      const int i = s >> 2, r = s & 3;
      const int q = q0 + wq0 + i * 16 + quad * 4 + r;
      cand[(size_t)q * 64 + split * 4 + wh * 2 + 0] = x1;  // disjoint per wave-half
      cand[(size_t)q * 64 + split * 4 + wh * 2 + 1] = x2;
    }
  }
}

// ---------------- kernel 3: fused top-4-of-64 select + exact fp64 rescore ----------------
// 16 lanes per query (4 queries/wave, grid 1024): local sorted-4 of 4 slots,
// butterfly sorted-4 merge over 16 lanes, fp64 rescore of the 4 survivors.
__global__ __launch_bounds__(256) void k_pick(const float* __restrict__ zT,
                                              const float* __restrict__ emb,
                                              const u64* __restrict__ cand,
                                              int* __restrict__ idxF) {
  const int lane = threadIdx.x & 63;
  const int wv   = threadIdx.x >> 6;
  const int sub  = lane >> 4;
  const int l15  = lane & 15;
  const int q = (int)(blockIdx.x * 16) + wv * 4 + sub;

  // local sorted-4 (ascending) of my 4 slots
  u64 s0 = ~0ull, s1 = ~0ull, s2 = ~0ull, s3 = ~0ull;
  const u64* cp = cand + (size_t)q * 64 + l15 * 4;
#pragma unroll
  for (int j = 0; j < 4; ++j) {
    u64 v = cp[j];
    const u64 t0 = umin64(s0, v); v = umax64(s0, v); s0 = t0;
    const u64 t1 = umin64(s1, v); v = umax64(s1, v); s1 = t1;
    const u64 t2 = umin64(s2, v); v = umax64(s2, v); s2 = t2;
    s3 = umin64(s3, v);
  }
  // butterfly merge of sorted-4 lists over the 16-lane group
#pragma unroll
  for (int off = 1; off < 16; off <<= 1) {
    const u64 b0 = __shfl_xor(s0, off, 64);
    const u64 b1 = __shfl_xor(s1, off, 64);
    const u64 b2 = __shfl_xor(s2, off, 64);
    const u64 b3 = __shfl_xor(s3, off, 64);
    const u64 c0 = umin64(s0, b0);
    const u64 c1 = umin64(umin64(s1, b1), umax64(s0, b0));
    const u64 c2 = umin64(umin64(s2, b2),
                          umin64(umax64(s1, b0), umax64(s0, b1)));
    const u64 c3 = umin64(umin64(umin64(s3, b3), umax64(s2, b0)),
                          umin64(umax64(s0, b2), umax64(s1, b1)));
    s0 = c0; s1 = c1; s2 = c2; s3 = c3;
  }
  const u64 sel[4] = {s0, s1, s2, s3};

  // fp64 rescore: lane slice = 16 channels
  const float* zrow = zT + (size_t)q * CD + l15 * 16;
  const float4 za = *(const float4*)(zrow + 0);
  const float4 zb = *(const float4*)(zrow + 4);
  const float4 zc = *(const float4*)(zrow + 8);
  const float4 zd = *(const float4*)(zrow + 12);
  double bd = 1e300;
  int bi = 0x7fffffff;
#pragma unroll
  for (int t = 0; t < 4; ++t) {
    const int idx = (int)(unsigned)(sel[t] & 0xffffffffull);
    const float* er = emb + (size_t)idx * CD + l15 * 16;
    const float4 ea = *(const float4*)(er + 0);
    const float4 eb = *(const float4*)(er + 4);
    const float4 ec = *(const float4*)(er + 8);
    const float4 ed = *(const float4*)(er + 12);
    double s = 0.0;
#define ACC1(zv, ev) { const double d = (double)(zv) - (double)(ev); s += d * d; }
    ACC1(za.x, ea.x) ACC1(za.y, ea.y) ACC1(za.z, ea.z) ACC1(za.w, ea.w)
    ACC1(zb.x, eb.x) ACC1(zb.y, eb.y) ACC1(zb.z, eb.z) ACC1(zb.w, eb.w)
    ACC1(zc.x, ec.x) ACC1(zc.y, ec.y) ACC1(zc.z, ec.z) ACC1(zc.w, ec.w)
    ACC1(zd.x, ed.x) ACC1(zd.y, ed.y) ACC1(zd.z, ed.z) ACC1(zd.w, ed.w)
#undef ACC1
#pragma unroll
    for (int off = 1; off < 16; off <<= 1) s += __shfl_xor(s, off, 64);
    if (s < bd || (s == bd && idx < bi)) { bd = s; bi = idx; }
  }
  if (l15 == 0) idxF[q] = bi;
}

// ---------------- kernel 4: gather out[b][c][hw] = emb[idx][c] (grid 256) ----------------
__global__ __launch_bounds__(256) void k_gather(const float* __restrict__ emb,
                                                const int* __restrict__ idxF,
                                                float* __restrict__ out) {
  const int b   = (int)(blockIdx.x >> 4);
  const int hw0 = (int)(blockIdx.x & 15) * 64;
  const int lane = threadIdx.x & 63;
  const int cg   = threadIdx.x >> 6;
  const int hw = hw0 + lane;
  const int k  = idxF[b * HW + hw];
  const float* er = emb + (size_t)k * CD + cg * 64;
  float* ob = out + (size_t)b * CD * HW + (size_t)(cg * 64) * HW + hw;
#pragma unroll
  for (int j = 0; j < 16; ++j) {
    const float4 e = *(const float4*)(er + j * 4);
    ob[(size_t)(j * 4 + 0) * HW] = e.x;
    ob[(size_t)(j * 4 + 1) * HW] = e.y;
    ob[(size_t)(j * 4 + 2) * HW] = e.z;
    ob[(size_t)(j * 4 + 3) * HW] = e.w;
  }
}

extern "C" void kernel_launch(void* const* d_in, const int* in_sizes, int n_in,
                              void* d_out, int out_size, void* d_ws, size_t ws_size,
                              hipStream_t stream) {
  const float* z   = (const float*)d_in[0];
  const float* emb = (const float*)d_in[1];
  float* out = (float*)d_out;

  char* ws = (char*)d_ws;
  float* zT   = (float*)(ws + ZT_OFF);
  u16*   zTb  = (u16*)(ws + ZTB_OFF);
  u16*   embB = (u16*)(ws + EMBB_OFF);
  float* eH   = (float*)(ws + EH_OFF);
  u64*   cand = (u64*)(ws + CAND_OFF);
  int*   idxF = (int*)(ws + IDX_OFF);

  k_prep<<<1280, 256, 0, stream>>>(z, emb, zT, zTb, embB, eH);
  k_argmin<<<2048, 256, 0, stream>>>(zTb, embB, eH, cand);
  k_pick<<<1024, 256, 0, stream>>>(zT, emb, cand, idxF);
  k_gather<<<256, 256, 0, stream>>>(emb, idxF, out);
}

// Round 7
// 186.339 us; speedup vs baseline: 6.3156x; 1.0902x over previous
//
#include <hip/hip_runtime.h>
#include <stdint.h>

#define NB   16
#define CD   256
#define HW   1024
#define NQ   16384
#define KCN  8192

typedef unsigned long long u64;
typedef unsigned short     u16;
using f32x4  = __attribute__((ext_vector_type(4))) float;
using bf16x8 = __attribute__((ext_vector_type(8))) __bf16;

// ---------------- workspace layout (~32.8 MB) ----------------
#define ZT_OFF   0            // f32  [NQ][CD]   16 MB  (z transposed, fp32)
#define ZTB_OFF  16777216     // u16  [NQ][CD]    8 MB  (z transposed, bf16)
#define EMBB_OFF 25165824     // u16  [KCN][CD]   4 MB  (emb, bf16)
#define EH_OFF   29360128     // f32  [KCN]      32 KB  (||e||^2/2 + 1024)
#define CAND_OFF 29392896     // u64  [NQ][32]    4 MB  (8 splits x 2 halves x top-2)

static __device__ __forceinline__ void gl_lds16(const void* g, void* l) {
  __builtin_amdgcn_global_load_lds(
      (const __attribute__((address_space(1))) void*)g,
      (__attribute__((address_space(3))) void*)l, 16, 0, 0);
}

static __device__ __forceinline__ unsigned bf16r(float x) {  // RNE fp32->bf16 bits
  unsigned u = __float_as_uint(x);
  return (u + 0x7fffu + ((u >> 16) & 1u)) >> 16;
}

static __device__ __forceinline__ u64 umin64(u64 a, u64 b) { return a < b ? a : b; }
static __device__ __forceinline__ u64 umax64(u64 a, u64 b) { return a < b ? b : a; }

// ---------------- kernel 1: merged prep ----------------
__global__ __launch_bounds__(256) void k_prep(const float* __restrict__ z,
                                              const float* __restrict__ emb,
                                              float* __restrict__ zT,
                                              u16* __restrict__ zTb,
                                              u16* __restrict__ embB,
                                              float* __restrict__ eH) {
  const int bx = (int)blockIdx.x;
  if (bx < 1024) {
    __shared__ float tile[64][65];
    const int b   = bx >> 6;
    const int hwT = (bx >> 2) & 15;
    const int cT  = bx & 3;
    const int tx  = threadIdx.x & 63;
    const int ty  = threadIdx.x >> 6;
    const float* src = z + (size_t)(b * CD + cT * 64) * HW + hwT * 64;
#pragma unroll
    for (int i = 0; i < 16; ++i) {
      const int c_l = ty + 4 * i;
      tile[c_l][tx] = src[(size_t)c_l * HW + tx];
    }
    __syncthreads();
    const size_t dbase = (size_t)(b * HW + hwT * 64) * CD + cT * 64;
#pragma unroll
    for (int i = 0; i < 16; ++i) {
      const int hw_l = ty + 4 * i;
      const float v = tile[tx][hw_l];
      zT [dbase + (size_t)hw_l * CD + tx] = v;
      zTb[dbase + (size_t)hw_l * CD + tx] = (u16)bf16r(v);
    }
  } else {
    const int wave = (bx - 1024) * 4 + ((int)threadIdx.x >> 6);  // 0..1023
    const int lane = threadIdx.x & 63;
#pragma unroll
    for (int it = 0; it < 8; ++it) {
      const int row = wave * 8 + it;
      const float4 v = *(const float4*)(emb + (size_t)row * CD + lane * 4);
      uint2 pk;
      pk.x = bf16r(v.x) | (bf16r(v.y) << 16);
      pk.y = bf16r(v.z) | (bf16r(v.w) << 16);
      *(uint2*)(embB + (size_t)row * CD + lane * 4) = pk;
      float s = v.x * v.x + v.y * v.y + v.z * v.z + v.w * v.w;
#pragma unroll
      for (int off = 32; off; off >>= 1) s += __shfl_xor(s, off, 64);
      if (lane == 0) eH[row] = 0.5f * s + 1024.0f;
    }
  }
}

// ---------------- kernel 2: MFMA GEMM + fused top-2 argmin (R4 tile/splits, fp32 epilogue) ----
// grid = 128 q-tiles * 8 splits = 1024; block 256 = 4 waves; wave w: queries (w&1)*64..+64,
// codes (w>>1)*64..+64. NT=8 n-tiles/block; K=256 in 4 chunks of BK=64. LDS XOR-swizzled
// (R4-measured: 0 bank conflicts). Epilogue keys = fp32 quantized to 32 ulp with 5-bit
// (nt,j) id embedded in the cleared mantissa bits -> all per-nt tournament ops are fp32.
#define NT  8
#define BKC 4

__global__ __launch_bounds__(256, 2) void k_argmin(const u16* __restrict__ zTb,
                                                   const u16* __restrict__ embB,
                                                   const float* __restrict__ eH,
                                                   u64* __restrict__ cand) {
  __shared__ __align__(16) u16 As[128 * 64];
  __shared__ __align__(16) u16 Bs[128 * 64];
  const int tid  = threadIdx.x;
  const int w    = tid >> 6;
  const int lane = tid & 63;
  const int l15  = lane & 15, quad = lane >> 4, l7 = lane & 7;
  const int q0    = (int)(blockIdx.x >> 3) * 128;
  const int split = (int)(blockIdx.x & 7);
  const int wq0 = (w & 1) * 64, wn0 = (w >> 1) * 64, wh = w >> 1;

  const int srow  = w * 32 + (lane >> 3);          // + i*8
  const int scol8 = (l7 ^ (lane >> 3)) * 8;        // logical chunk * 8 elems
  const int ldsL  = w * 4096 + lane * 16;          // byte offset, + i*1024
  const int co0 = ((0 * 4 + quad) ^ l7) * 16;
  const int co1 = ((1 * 4 + quad) ^ l7) * 16;

  const float FMAX = __uint_as_float(0x7F7FFFFFu);
  float b1[16], b2[16];
#pragma unroll
  for (int s = 0; s < 16; ++s) { b1[s] = FMAX; b2[s] = FMAX; }

  for (int nt = 0; nt < NT; ++nt) {
    const int n0 = split * 1024 + nt * 128;
    float eh[4];
#pragma unroll
    for (int j = 0; j < 4; ++j) eh[j] = eH[n0 + wn0 + 16 * j + l15];

    f32x4 acc[4][4];
#pragma unroll
    for (int i = 0; i < 4; ++i)
#pragma unroll
      for (int j = 0; j < 4; ++j) acc[i][j] = f32x4{0.f, 0.f, 0.f, 0.f};

    for (int kc = 0; kc < BKC; ++kc) {
#pragma unroll
      for (int i = 0; i < 4; ++i) {
        const int row = srow + i * 8;
        gl_lds16(zTb  + (size_t)(q0 + row) * CD + kc * 64 + scol8,
                 (char*)As + ldsL + i * 1024);
        gl_lds16(embB + (size_t)(n0 + row) * CD + kc * 64 + scol8,
                 (char*)Bs + ldsL + i * 1024);
      }
      __syncthreads();
#pragma unroll
      for (int ks = 0; ks < 2; ++ks) {
        const int co = ks ? co1 : co0;
        bf16x8 af[4], bfr[4];
#pragma unroll
        for (int i = 0; i < 4; ++i)
          af[i] = *(const bf16x8*)((const char*)As + (wq0 + i * 16 + l15) * 128 + co);
#pragma unroll
        for (int j = 0; j < 4; ++j)
          bfr[j] = *(const bf16x8*)((const char*)Bs + (wn0 + j * 16 + l15) * 128 + co);
#pragma unroll
        for (int i = 0; i < 4; ++i)
#pragma unroll
          for (int j = 0; j < 4; ++j)
            acc[i][j] = __builtin_amdgcn_mfma_f32_16x16x32_bf16(af[i], bfr[j],
                                                                acc[i][j], 0, 0, 0);
      }
      __syncthreads();
    }
    // ---- fp32 epilogue: key = (||e||^2/2+1024) - z.e, quantized, id=(nt*4+j) in low 5 bits
#pragma unroll
    for (int i = 0; i < 4; ++i) {
#pragma unroll
      for (int r = 0; r < 4; ++r) {
        const int s = i * 4 + r;
        float kq[4];
#pragma unroll
        for (int j = 0; j < 4; ++j) {
          const unsigned kb = (__float_as_uint(eh[j] - acc[i][j][r]) & ~31u)
                              | (unsigned)(nt * 4 + j);
          kq[j] = __uint_as_float(kb);
        }
        const float lo01 = fminf(kq[0], kq[1]), hi01 = fmaxf(kq[0], kq[1]);
        const float lo23 = fminf(kq[2], kq[3]), hi23 = fmaxf(kq[2], kq[3]);
        const float best = fminf(lo01, lo23);
        const float sec  = fminf(fmaxf(lo01, lo23), fminf(hi01, hi23));
        b2[s] = fminf(fmaxf(best, b1[s]), fminf(sec, b2[s]));
        b1[s] = fminf(best, b1[s]);
      }
    }
  }
  // ---- once per block: u64 butterfly top-2 merge (lane id in low bits), write cand
#pragma unroll
  for (int s = 0; s < 16; ++s) {
    u64 x1 = ((u64)__float_as_uint(b1[s]) << 32) | (unsigned)l15;
    u64 x2 = ((u64)__float_as_uint(b2[s]) << 32) | (unsigned)l15;
#pragma unroll
    for (int off = 1; off < 16; off <<= 1) {
      const u64 o1 = __shfl_xor(x1, off, 64);
      const u64 o2 = __shfl_xor(x2, off, 64);
      const u64 lo = umin64(x1, o1);
      const u64 hi = umax64(x1, o1);
      x1 = lo;
      x2 = umin64(hi, umin64(x2, o2));
    }
    if (l15 == 0) {
      const int i = s >> 2, r = s & 3;
      const int q = q0 + wq0 + i * 16 + quad * 4 + r;
      // reconstruct code index n from embedded bits
      const unsigned kb1 = (unsigned)(x1 >> 32), kb2 = (unsigned)(x2 >> 32);
      const int n1 = split * 1024 + (int)((kb1 >> 2) & 7) * 128 + wn0
                     + 16 * (int)(kb1 & 3) + (int)(x1 & 15);
      const int n2 = split * 1024 + (int)((kb2 >> 2) & 7) * 128 + wn0
                     + 16 * (int)(kb2 & 3) + (int)(x2 & 15);
      cand[(size_t)q * 32 + split * 4 + wh * 2 + 0] = ((u64)kb1 << 32) | (unsigned)n1;
      cand[(size_t)q * 32 + split * 4 + wh * 2 + 1] = ((u64)kb2 << 32) | (unsigned)n2;
    }
  }
}

// ---------------- kernel 3: fused select + fp64 rescore + output gather/transpose ----------
// grid 1024, 16 consecutive queries per block (same b). 16 lanes/query: local sorted-2
// (+inf pad to sorted-4), butterfly sorted-4 merge over 16 lanes, fp64 rescore of the 4
// survivors, then winner's emb row -> LDS [hw][c] tile -> coalesced strided store to out.
__global__ __launch_bounds__(256) void k_pick_out(const float* __restrict__ zT,
                                                  const float* __restrict__ emb,
                                                  const u64* __restrict__ cand,
                                                  float* __restrict__ out) {
  __shared__ float tile[16][257];
  const int lane = threadIdx.x & 63;
  const int wv   = threadIdx.x >> 6;
  const int sub  = lane >> 4;
  const int l15  = lane & 15;
  const int q0b  = (int)blockIdx.x * 16;
  const int q    = q0b + wv * 4 + sub;
  const int hwl  = wv * 4 + sub;

  // local sorted-4 from my 2 slots (+inf padding)
  const u64* cp = cand + (size_t)q * 32 + l15 * 2;
  const u64 v0 = cp[0], v1 = cp[1];
  u64 s0 = umin64(v0, v1), s1 = umax64(v0, v1), s2 = ~0ull, s3 = ~0ull;
  // butterfly merge of sorted-4 lists over the 16-lane group
#pragma unroll
  for (int off = 1; off < 16; off <<= 1) {
    const u64 b0 = __shfl_xor(s0, off, 64);
    const u64 b1 = __shfl_xor(s1, off, 64);
    const u64 b2 = __shfl_xor(s2, off, 64);
    const u64 b3 = __shfl_xor(s3, off, 64);
    const u64 c0 = umin64(s0, b0);
    const u64 c1 = umin64(umin64(s1, b1), umax64(s0, b0));
    const u64 c2 = umin64(umin64(s2, b2),
                          umin64(umax64(s1, b0), umax64(s0, b1)));
    const u64 c3 = umin64(umin64(umin64(s3, b3), umax64(s2, b0)),
                          umin64(umax64(s0, b2), umax64(s1, b1)));
    s0 = c0; s1 = c1; s2 = c2; s3 = c3;
  }
  const u64 sel[4] = {s0, s1, s2, s3};

  // fp64 rescore: lane slice = 16 channels
  const float* zrow = zT + (size_t)q * CD + l15 * 16;
  const float4 za = *(const float4*)(zrow + 0);
  const float4 zb = *(const float4*)(zrow + 4);
  const float4 zc = *(const float4*)(zrow + 8);
  const float4 zd = *(const float4*)(zrow + 12);
  double bd = 1e300;
  int bi = 0x7fffffff;
#pragma unroll
  for (int t = 0; t < 4; ++t) {
    const int idx = (int)(unsigned)(sel[t] & 0xffffffffull);
    const float* er = emb + (size_t)idx * CD + l15 * 16;
    const float4 ea = *(const float4*)(er + 0);
    const float4 eb = *(const float4*)(er + 4);
    const float4 ec = *(const float4*)(er + 8);
    const float4 ed = *(const float4*)(er + 12);
    double s = 0.0;
#define ACC1(zv, ev) { const double d = (double)(zv) - (double)(ev); s += d * d; }
    ACC1(za.x, ea.x) ACC1(za.y, ea.y) ACC1(za.z, ea.z) ACC1(za.w, ea.w)
    ACC1(zb.x, eb.x) ACC1(zb.y, eb.y) ACC1(zb.z, eb.z) ACC1(zb.w, eb.w)
    ACC1(zc.x, ec.x) ACC1(zc.y, ec.y) ACC1(zc.z, ec.z) ACC1(zc.w, ec.w)
    ACC1(zd.x, ed.x) ACC1(zd.y, ed.y) ACC1(zd.z, ed.z) ACC1(zd.w, ed.w)
#undef ACC1
#pragma unroll
    for (int off = 1; off < 16; off <<= 1) s += __shfl_xor(s, off, 64);
    if (s < bd || (s == bd && idx < bi)) { bd = s; bi = idx; }
  }
  // winner row -> LDS tile (all 16 lanes of the group agree on bi)
  {
    const float* er = emb + (size_t)bi * CD + l15 * 16;
    const float4 ea = *(const float4*)(er + 0);
    const float4 eb = *(const float4*)(er + 4);
    const float4 ec = *(const float4*)(er + 8);
    const float4 ed = *(const float4*)(er + 12);
    *(float4*)&tile[hwl][l15 * 16 + 0]  = ea;
    *(float4*)&tile[hwl][l15 * 16 + 4]  = eb;
    *(float4*)&tile[hwl][l15 * 16 + 8]  = ec;
    *(float4*)&tile[hwl][l15 * 16 + 12] = ed;
  }
  __syncthreads();
  // store phase: thread t = channel c; 16 hw values contiguous
  const int t = threadIdx.x;
  const int b = q0b >> 10, hw0 = q0b & 1023;
  float* optr = out + (size_t)b * CD * HW + (size_t)t * HW + hw0;
  float v[16];
#pragma unroll
  for (int j = 0; j < 16; ++j) v[j] = tile[j][t];
#pragma unroll
  for (int m = 0; m < 4; ++m) {
    float4 f; f.x = v[4 * m]; f.y = v[4 * m + 1]; f.z = v[4 * m + 2]; f.w = v[4 * m + 3];
    *(float4*)(optr + 4 * m) = f;
  }
}

extern "C" void kernel_launch(void* const* d_in, const int* in_sizes, int n_in,
                              void* d_out, int out_size, void* d_ws, size_t ws_size,
                              hipStream_t stream) {
  const float* z   = (const float*)d_in[0];
  const float* emb = (const float*)d_in[1];
  float* out = (float*)d_out;

  char* ws = (char*)d_ws;
  float* zT   = (float*)(ws + ZT_OFF);
  u16*   zTb  = (u16*)(ws + ZTB_OFF);
  u16*   embB = (u16*)(ws + EMBB_OFF);
  float* eH   = (float*)(ws + EH_OFF);
  u64*   cand = (u64*)(ws + CAND_OFF);

  k_prep<<<1280, 256, 0, stream>>>(z, emb, zT, zTb, embB, eH);
  k_argmin<<<1024, 256, 0, stream>>>(zTb, embB, eH, cand);
  k_pick_out<<<1024, 256, 0, stream>>>(zT, emb, cand, out);
}